// Round 12
// baseline (31533.771 us; speedup 1.0000x reference)
//
#include <hip/hip_runtime.h>
#include <hip/hip_bf16.h>

// EnvLSTM: T=4096, IN=MEM=OUT=1024, fp32 in/out.
// r8: np ref is f64-class; per-step noise budget ~1e-10 (ampl ~2.4e7).
// r10: recur 21ms at 5.1us/step (chain = flag RTT + data RTT).
// r11: tagged mailboxes (data IS the flag, 1 RTT) -- HUNG: init_k wrote dir-1
//      parity-0 tags out of bounds (comm[(4096+j)*2] instead of (2048+j)*2),
//      dir-1 consumers polled poison forever.
// r12: fix indexing; init rewrites ALL comm words each launch (parity-1 gets
//      sentinel tag 0xFFFFFFFF) -- kills both the deadlock and a replay
//      staleness race (harness does not re-poison between graph replays).
//   P1/P3: r8-verified VALU f64 GEMMs, unchanged.

typedef __attribute__((ext_vector_type(4))) float f32x4;

static constexpr int TSEQ = 4096;
typedef unsigned long long ull;

struct Ptr6 { const float* p[6]; };

__device__ inline void atomic_store_u64(ull* p, ull v) {
  __hip_atomic_store(p, v, __ATOMIC_RELAXED, __HIP_MEMORY_SCOPE_AGENT);
}
__device__ inline ull atomic_load_u64(ull* p) {
  return __hip_atomic_load(p, __ATOMIC_RELAXED, __HIP_MEMORY_SCOPE_AGENT);
}

// comm word index = dir*4096 + parity*2048 + cell*2 + w
// word = (tag:u32 << 32) | f64-half:u32 ; w0 = bits[31:0], w1 = bits[63:32]

// ---------------- init: rewrite ALL comm words + env boundary rows ----------------
__global__ void init_k(const float* __restrict__ c0l, const float* __restrict__ c0r,
                       ull* __restrict__ comm, float* __restrict__ env) {
  int tid = blockIdx.x * blockDim.x + threadIdx.x;  // grid 8*256 = 2048
  if (tid >= 2048) return;
  const int dirv = tid >> 10, j = tid & 1023;
  const double v = (double)(dirv ? c0r[j] : c0l[j]);
  const ull bits = __builtin_bit_cast(ull, v);
  ull* base = comm + (size_t)dirv * 4096;
  // parity 0: tag 0 + c0 payload
  atomic_store_u64(&base[2 * j], bits & 0xffffffffull);
  atomic_store_u64(&base[2 * j + 1], bits >> 32);
  // parity 1: sentinel tag (never matches any wanted t <= 4094)
  atomic_store_u64(&base[2048 + 2 * j], 0xFFFFFFFF00000000ull);
  atomic_store_u64(&base[2048 + 2 * j + 1], 0xFFFFFFFF00000000ull);
  if (dirv == 0) env[j] = (float)v;                                  // lenv[0]
  else env[(size_t)(TSEQ - 1) * 2048 + 1024 + j] = (float)v;         // renv[T-1]
}

// ---------------- VALU f64 GEMM P1: Wx[4096][6144] = x @ W^T + b ----------------
// Stores f32 hi + bf16 lo. [r8-verified]
__global__ __launch_bounds__(256) void gemm_f64v_k(
    const float* __restrict__ A, Ptr6 B, Ptr6 BIAS,
    float* __restrict__ CH, __hip_bfloat16* __restrict__ CL) {
  __shared__ double As[16][66];
  __shared__ double Bs[16][66];
  const int tid = threadIdx.x;
  const int m0 = blockIdx.y * 64, n0 = blockIdx.x * 64;
  const int tx = tid & 15, ty = tid >> 4;
  const int lrow = tid >> 2, lkq = tid & 3;
  const float* bmat = B.p[n0 >> 10] + (size_t)(n0 & 1023) * 1024;

  double acc[4][4] = {};

  for (int k0 = 0; k0 < 1024; k0 += 16) {
    f32x4 va = *(const f32x4*)(A + (size_t)(m0 + lrow) * 1024 + k0 + lkq * 4);
    f32x4 vb = *(const f32x4*)(bmat + (size_t)lrow * 1024 + k0 + lkq * 4);
    __syncthreads();
#pragma unroll
    for (int e = 0; e < 4; ++e) {
      As[lkq * 4 + e][lrow] = (double)va[e];
      Bs[lkq * 4 + e][lrow] = (double)vb[e];
    }
    __syncthreads();
#pragma unroll
    for (int k = 0; k < 16; ++k) {
      double a[4], b[4];
#pragma unroll
      for (int i = 0; i < 4; ++i) a[i] = As[k][ty + 16 * i];
#pragma unroll
      for (int jj = 0; jj < 4; ++jj) b[jj] = Bs[k][tx + 16 * jj];
#pragma unroll
      for (int i = 0; i < 4; ++i)
#pragma unroll
        for (int jj = 0; jj < 4; ++jj)
          acc[i][jj] = fma(a[i], b[jj], acc[i][jj]);
    }
  }

#pragma unroll
  for (int i = 0; i < 4; ++i)
#pragma unroll
    for (int jj = 0; jj < 4; ++jj) {
      int row = m0 + ty + 16 * i;
      int col = n0 + tx + 16 * jj;
      double s = acc[i][jj] + (double)BIAS.p[col >> 10][col & 1023];
      size_t idx = (size_t)row * 6144 + col;
      float hi = (float)s;
      CH[idx] = hi;
      CL[idx] = __float2bfloat16((float)(s - (double)hi));
    }
}

// ---------------- persistent f64 recurrence: tagged mailboxes ----------------
__global__ __launch_bounds__(512, 2) void recur_k(
    const float* __restrict__ u0, const float* __restrict__ u1, const float* __restrict__ u2,
    const float* __restrict__ u3, const float* __restrict__ u4, const float* __restrict__ u5,
    const float* __restrict__ WxH,           // [T][6144] f32 hi
    const __hip_bfloat16* __restrict__ WxL,  // [T][6144] bf16 lo
    ull* __restrict__ comm,                  // [2dir][2parity][1024][2] tagged words
    float* __restrict__ env)                 // [T][2048] f32
{
  const int bid = blockIdx.x;     // 0..255
  const int dir = bid >> 7;
  const int wg  = bid & 127;
  const int tid = threadIdx.x;    // 0..511
  const int wave = tid >> 6;      // 0..7
  const int lane = tid & 63;
  const int j = wg * 8 + wave;    // cell owned by this wave

  const float* Uf = dir ? u3 : u0;
  const float* Ui = dir ? u4 : u1;
  const float* Uc = dir ? u5 : u2;

  // U rows as f64 in VGPRs: lane covers k = q*64 + lane (48 f64 = 96 VGPR)
  double wf[16], wi[16], wcc[16];
#pragma unroll
  for (int q = 0; q < 16; ++q) {
    const size_t idx = (size_t)j * 1024 + q * 64 + lane;
    wf[q] = (double)Uf[idx]; wi[q] = (double)Ui[idx]; wcc[q] = (double)Uc[idx];
  }

  __shared__ double cl[2][1024];  // double-buffered -> single barrier per step
  const size_t wxoff = (size_t)dir * 3072 + j;
  float* envp = env + dir * 1024 + j;
  ull* commd = comm + (size_t)dir * 4096;

  for (int t = 0; t < TSEQ - 1; ++t) {
    const int xr = dir ? (TSEQ - 1 - t) : t;
    const size_t base = (size_t)xr * 6144 + wxoff;
    // Wx prefetch (stable, L2-cached; no fences anywhere)
    const double wxf = (double)WxH[base] + (double)__bfloat162float(WxL[base]);
    const double wxi = (double)WxH[base + 1024] + (double)__bfloat162float(WxL[base + 1024]);
    const double wxg = (double)WxH[base + 2048] + (double)__bfloat162float(WxL[base + 2048]);

    // poll own 2 cells (4 words) until tag == t; data IS the flag -> 1 RTT
    {
      ull* src = commd + (size_t)(t & 1) * 2048 + 4 * tid;
      const unsigned want = (unsigned)t;
      ull w0, w1, w2, w3;
      for (;;) {
        w0 = atomic_load_u64(src);
        w1 = atomic_load_u64(src + 1);
        w2 = atomic_load_u64(src + 2);
        w3 = atomic_load_u64(src + 3);
        if ((unsigned)(w0 >> 32) == want && (unsigned)(w1 >> 32) == want &&
            (unsigned)(w2 >> 32) == want && (unsigned)(w3 >> 32) == want)
          break;
        __builtin_amdgcn_s_sleep(1);
      }
      cl[t & 1][2 * tid] =
          __builtin_bit_cast(double, (w0 & 0xffffffffull) | (w1 << 32));
      cl[t & 1][2 * tid + 1] =
          __builtin_bit_cast(double, (w2 & 0xffffffffull) | (w3 << 32));
    }
    __syncthreads();  // staging complete; tag chain covers the WAR side

    const double* c = cl[t & 1];
    const double cold = c[j];
    double sf = 0.0, si = 0.0, sg = 0.0;
#pragma unroll
    for (int q = 0; q < 16; ++q) {
      const double cc = c[q * 64 + lane];
      sf = fma(wf[q], cc, sf);
      si = fma(wi[q], cc, si);
      sg = fma(wcc[q], cc, sg);
    }
#pragma unroll
    for (int off = 1; off < 64; off <<= 1) {
      sf += __shfl_xor(sf, off);
      si += __shfl_xor(si, off);
      sg += __shfl_xor(sg, off);
    }

    const double af = sf + wxf, ai = si + wxi, ag = sg + wxg;
    const double fgate = 1.0 / (1.0 + exp(-af));
    const double igate = 1.0 / (1.0 + exp(-ai));
    const double ggate = tanh(ag);
    const double cn = fgate * cold + igate * ggate;

    if (lane == 0) {
      const ull bits = __builtin_bit_cast(ull, cn);
      const ull tag = (ull)(unsigned)(t + 1) << 32;
      ull* dst = commd + (size_t)((t + 1) & 1) * 2048 + (size_t)j * 2;
      atomic_store_u64(dst, (bits & 0xffffffffull) | tag);
      atomic_store_u64(dst + 1, (bits >> 32) | tag);
      const int er = dir ? (TSEQ - 2 - t) : (t + 1);
      envp[(size_t)er * 2048] = (float)cn;
    }
  }
}

// ---------------- VALU f64 GEMM P3: out = tanh(env @ [wo|uo]^T + bo) ----------------
__global__ __launch_bounds__(256) void gemm_out_f64_k(
    const float* __restrict__ A, const float* __restrict__ wo,
    const float* __restrict__ uo, const float* __restrict__ bo,
    float* __restrict__ C) {
  __shared__ double As[16][66];
  __shared__ double Bs[16][66];
  const int tid = threadIdx.x;
  const int m0 = blockIdx.y * 64, n0 = blockIdx.x * 64;
  const int tx = tid & 15, ty = tid >> 4;
  const int lrow = tid >> 2, lkq = tid & 3;

  double acc[4][4] = {};

  for (int k0 = 0; k0 < 2048; k0 += 16) {
    f32x4 va = *(const f32x4*)(A + (size_t)(m0 + lrow) * 2048 + k0 + lkq * 4);
    const float* bsrc = (k0 < 1024)
        ? wo + (size_t)(n0 + lrow) * 1024 + k0 + lkq * 4
        : uo + (size_t)(n0 + lrow) * 1024 + (k0 - 1024) + lkq * 4;
    f32x4 vb = *(const f32x4*)bsrc;
    __syncthreads();
#pragma unroll
    for (int e = 0; e < 4; ++e) {
      As[lkq * 4 + e][lrow] = (double)va[e];
      Bs[lkq * 4 + e][lrow] = (double)vb[e];
    }
    __syncthreads();
#pragma unroll
    for (int k = 0; k < 16; ++k) {
      double a[4], b[4];
#pragma unroll
      for (int i = 0; i < 4; ++i) a[i] = As[k][ty + 16 * i];
#pragma unroll
      for (int jj = 0; jj < 4; ++jj) b[jj] = Bs[k][tx + 16 * jj];
#pragma unroll
      for (int i = 0; i < 4; ++i)
#pragma unroll
        for (int jj = 0; jj < 4; ++jj)
          acc[i][jj] = fma(a[i], b[jj], acc[i][jj]);
    }
  }

#pragma unroll
  for (int i = 0; i < 4; ++i)
#pragma unroll
    for (int jj = 0; jj < 4; ++jj) {
      int row = m0 + ty + 16 * i;
      int col = n0 + tx + 16 * jj;
      double s = acc[i][jj] + (double)bo[col];
      C[(size_t)row * 1024 + col] = (float)tanh(s);
    }
}

// ---------------- launch ----------------
extern "C" void kernel_launch(void* const* d_in, const int* in_sizes, int n_in,
                              void* d_out, int out_size, void* d_ws, size_t ws_size,
                              hipStream_t stream) {
  if (n_in < 24) return;
  const float* x    = (const float*)d_in[0];
  const float* wf_l = (const float*)d_in[1];
  const float* uf_l = (const float*)d_in[2];
  const float* bf_l = (const float*)d_in[3];
  const float* wi_l = (const float*)d_in[4];
  const float* ui_l = (const float*)d_in[5];
  const float* bi_l = (const float*)d_in[6];
  const float* wc_l = (const float*)d_in[7];
  const float* uc_l = (const float*)d_in[8];
  const float* bc_l = (const float*)d_in[9];
  const float* wf_r = (const float*)d_in[10];
  const float* uf_r = (const float*)d_in[11];
  const float* bf_r = (const float*)d_in[12];
  const float* wi_r = (const float*)d_in[13];
  const float* ui_r = (const float*)d_in[14];
  const float* bi_r = (const float*)d_in[15];
  const float* wc_r = (const float*)d_in[16];
  const float* uc_r = (const float*)d_in[17];
  const float* bc_r = (const float*)d_in[18];
  const float* wo   = (const float*)d_in[19];
  const float* uo   = (const float*)d_in[20];
  const float* bo   = (const float*)d_in[21];
  const float* c0l  = (const float*)d_in[22];
  const float* c0r  = (const float*)d_in[23];

  const size_t NWX = (size_t)TSEQ * 6144;
  char* p = (char*)d_ws;
  auto carve = [&](size_t bytes) -> char* {
    char* r = p; p += (bytes + 255) & ~(size_t)255; return r;
  };
  float*          WxH  = (float*)carve(NWX * 4);                  // 100.7 MB
  __hip_bfloat16* WxL  = (__hip_bfloat16*)carve(NWX * 2);         //  50.3 MB
  float*          envc = (float*)carve((size_t)TSEQ * 2048 * 4);  //  33.6 MB
  ull*            comm = (ull*)carve(8192 * 8);                   //  64 KB
  if ((size_t)(p - (char*)d_ws) > ws_size) return;

  init_k<<<8, 256, 0, stream>>>(c0l, c0r, comm, envc);

  Ptr6 Bw{{wf_l, wi_l, wc_l, wf_r, wi_r, wc_r}};
  Ptr6 Bb{{bf_l, bi_l, bc_l, bf_r, bi_r, bc_r}};
  gemm_f64v_k<<<dim3(96, 64), 256, 0, stream>>>(x, Bw, Bb, WxH, WxL);

  recur_k<<<256, 512, 0, stream>>>(uf_l, ui_l, uc_l, uf_r, ui_r, uc_r,
                                   WxH, WxL, comm, envc);

  gemm_out_f64_k<<<dim3(16, 64), 256, 0, stream>>>(envc, wo, uo, bo, (float*)d_out);
}

// Round 13
// 26153.314 us; speedup vs baseline: 1.2057x; 1.2057x over previous
//
#include <hip/hip_runtime.h>
#include <hip/hip_bf16.h>

// EnvLSTM: T=4096, IN=MEM=OUT=1024, fp32 in/out.
// r8: np ref f64-class; per-step noise budget ~1e-10.
// r10: flag+data (2 RTT) = 5.1us/step. r12: tagged mailbox but per-lane
//      STRIDED atomic polls -> MALL op-rate saturation = 7.2us/step (FETCH 2x).
// r13: SoA comm layout -> every poll instruction is lane-contiguous (8B stride,
//      wave-coalesced into 128B MALL transactions, ~16x fewer ops). Protocol,
//      tags, induction, LDS double-buffer unchanged from r12.
//   P1/P3: r8-verified VALU f64 GEMMs, unchanged.

typedef __attribute__((ext_vector_type(4))) float f32x4;

static constexpr int TSEQ = 4096;
typedef unsigned long long ull;

struct Ptr6 { const float* p[6]; };

__device__ inline void atomic_store_u64(ull* p, ull v) {
  __hip_atomic_store(p, v, __ATOMIC_RELAXED, __HIP_MEMORY_SCOPE_AGENT);
}
__device__ inline ull atomic_load_u64(ull* p) {
  return __hip_atomic_load(p, __ATOMIC_RELAXED, __HIP_MEMORY_SCOPE_AGENT);
}

// comm word index = dir*4096 + parity*2048 + half*1024 + cell
// word = (tag:u32 << 32) | payload:u32 ; half0 = f64 bits[31:0], half1 = bits[63:32]

// ---------------- init: rewrite ALL comm words + env boundary rows ----------------
__global__ void init_k(const float* __restrict__ c0l, const float* __restrict__ c0r,
                       ull* __restrict__ comm, float* __restrict__ env) {
  int tid = blockIdx.x * blockDim.x + threadIdx.x;  // grid 8*256 = 2048
  if (tid >= 2048) return;
  const int dirv = tid >> 10, j = tid & 1023;
  const double v = (double)(dirv ? c0r[j] : c0l[j]);
  const ull bits = __builtin_bit_cast(ull, v);
  ull* base = comm + (size_t)dirv * 4096;
  // parity 0: tag 0 + c0 payload halves
  atomic_store_u64(&base[j], bits & 0xffffffffull);
  atomic_store_u64(&base[1024 + j], bits >> 32);
  // parity 1: sentinel tag (never matches any wanted t <= 4094)
  atomic_store_u64(&base[2048 + j], 0xFFFFFFFF00000000ull);
  atomic_store_u64(&base[2048 + 1024 + j], 0xFFFFFFFF00000000ull);
  if (dirv == 0) env[j] = (float)v;                                  // lenv[0]
  else env[(size_t)(TSEQ - 1) * 2048 + 1024 + j] = (float)v;         // renv[T-1]
}

// ---------------- VALU f64 GEMM P1: Wx[4096][6144] = x @ W^T + b ----------------
// Stores f32 hi + bf16 lo. [r8-verified]
__global__ __launch_bounds__(256) void gemm_f64v_k(
    const float* __restrict__ A, Ptr6 B, Ptr6 BIAS,
    float* __restrict__ CH, __hip_bfloat16* __restrict__ CL) {
  __shared__ double As[16][66];
  __shared__ double Bs[16][66];
  const int tid = threadIdx.x;
  const int m0 = blockIdx.y * 64, n0 = blockIdx.x * 64;
  const int tx = tid & 15, ty = tid >> 4;
  const int lrow = tid >> 2, lkq = tid & 3;
  const float* bmat = B.p[n0 >> 10] + (size_t)(n0 & 1023) * 1024;

  double acc[4][4] = {};

  for (int k0 = 0; k0 < 1024; k0 += 16) {
    f32x4 va = *(const f32x4*)(A + (size_t)(m0 + lrow) * 1024 + k0 + lkq * 4);
    f32x4 vb = *(const f32x4*)(bmat + (size_t)lrow * 1024 + k0 + lkq * 4);
    __syncthreads();
#pragma unroll
    for (int e = 0; e < 4; ++e) {
      As[lkq * 4 + e][lrow] = (double)va[e];
      Bs[lkq * 4 + e][lrow] = (double)vb[e];
    }
    __syncthreads();
#pragma unroll
    for (int k = 0; k < 16; ++k) {
      double a[4], b[4];
#pragma unroll
      for (int i = 0; i < 4; ++i) a[i] = As[k][ty + 16 * i];
#pragma unroll
      for (int jj = 0; jj < 4; ++jj) b[jj] = Bs[k][tx + 16 * jj];
#pragma unroll
      for (int i = 0; i < 4; ++i)
#pragma unroll
        for (int jj = 0; jj < 4; ++jj)
          acc[i][jj] = fma(a[i], b[jj], acc[i][jj]);
    }
  }

#pragma unroll
  for (int i = 0; i < 4; ++i)
#pragma unroll
    for (int jj = 0; jj < 4; ++jj) {
      int row = m0 + ty + 16 * i;
      int col = n0 + tx + 16 * jj;
      double s = acc[i][jj] + (double)BIAS.p[col >> 10][col & 1023];
      size_t idx = (size_t)row * 6144 + col;
      float hi = (float)s;
      CH[idx] = hi;
      CL[idx] = __float2bfloat16((float)(s - (double)hi));
    }
}

// ---------------- persistent f64 recurrence: coalesced tagged mailboxes ----------------
__global__ __launch_bounds__(512, 2) void recur_k(
    const float* __restrict__ u0, const float* __restrict__ u1, const float* __restrict__ u2,
    const float* __restrict__ u3, const float* __restrict__ u4, const float* __restrict__ u5,
    const float* __restrict__ WxH,           // [T][6144] f32 hi
    const __hip_bfloat16* __restrict__ WxL,  // [T][6144] bf16 lo
    ull* __restrict__ comm,                  // [2dir][2parity][2half][1024] tagged words
    float* __restrict__ env)                 // [T][2048] f32
{
  const int bid = blockIdx.x;     // 0..255
  const int dir = bid >> 7;
  const int wg  = bid & 127;
  const int tid = threadIdx.x;    // 0..511
  const int wave = tid >> 6;      // 0..7
  const int lane = tid & 63;
  const int j = wg * 8 + wave;    // cell owned by this wave

  const float* Uf = dir ? u3 : u0;
  const float* Ui = dir ? u4 : u1;
  const float* Uc = dir ? u5 : u2;

  // U rows as f64 in VGPRs: lane covers k = q*64 + lane (48 f64 = 96 VGPR)
  double wf[16], wi[16], wcc[16];
#pragma unroll
  for (int q = 0; q < 16; ++q) {
    const size_t idx = (size_t)j * 1024 + q * 64 + lane;
    wf[q] = (double)Uf[idx]; wi[q] = (double)Ui[idx]; wcc[q] = (double)Uc[idx];
  }

  __shared__ double cl[2][1024];  // double-buffered -> single barrier per step
  const size_t wxoff = (size_t)dir * 3072 + j;
  float* envp = env + dir * 1024 + j;
  ull* commd = comm + (size_t)dir * 4096;

  for (int t = 0; t < TSEQ - 1; ++t) {
    const int xr = dir ? (TSEQ - 1 - t) : t;
    const size_t base = (size_t)xr * 6144 + wxoff;
    // Wx prefetch (stable, L2/L3-cached; overlaps the poll wait)
    const double wxf = (double)WxH[base] + (double)__bfloat162float(WxL[base]);
    const double wxi = (double)WxH[base + 1024] + (double)__bfloat162float(WxL[base + 1024]);
    const double wxg = (double)WxH[base + 2048] + (double)__bfloat162float(WxL[base + 2048]);

    // poll 4 words, each load instruction lane-contiguous (wave-coalesced):
    // words {tid, tid+512, tid+1024, tid+1536} = both halves of cells tid, tid+512
    {
      ull* src = commd + (size_t)(t & 1) * 2048 + tid;
      const unsigned want = (unsigned)t;
      ull w0, w1, w2, w3;
      for (;;) {
        w0 = atomic_load_u64(src);          // half0, cell tid
        w1 = atomic_load_u64(src + 512);    // half0, cell tid+512
        w2 = atomic_load_u64(src + 1024);   // half1, cell tid
        w3 = atomic_load_u64(src + 1536);   // half1, cell tid+512
        if (((unsigned)(w0 >> 32) == want) & ((unsigned)(w1 >> 32) == want) &
            ((unsigned)(w2 >> 32) == want) & ((unsigned)(w3 >> 32) == want))
          break;
        __builtin_amdgcn_s_sleep(2);
      }
      cl[t & 1][tid] =
          __builtin_bit_cast(double, (w0 & 0xffffffffull) | (w2 << 32));
      cl[t & 1][tid + 512] =
          __builtin_bit_cast(double, (w1 & 0xffffffffull) | (w3 << 32));
    }
    __syncthreads();  // staging complete; tag chain covers the WAR side

    const double* c = cl[t & 1];
    const double cold = c[j];
    double sf = 0.0, si = 0.0, sg = 0.0;
#pragma unroll
    for (int q = 0; q < 16; ++q) {
      const double cc = c[q * 64 + lane];
      sf = fma(wf[q], cc, sf);
      si = fma(wi[q], cc, si);
      sg = fma(wcc[q], cc, sg);
    }
#pragma unroll
    for (int off = 1; off < 64; off <<= 1) {
      sf += __shfl_xor(sf, off);
      si += __shfl_xor(si, off);
      sg += __shfl_xor(sg, off);
    }

    const double af = sf + wxf, ai = si + wxi, ag = sg + wxg;
    const double fgate = 1.0 / (1.0 + exp(-af));
    const double igate = 1.0 / (1.0 + exp(-ai));
    const double ggate = tanh(ag);
    const double cn = fgate * cold + igate * ggate;

    if (lane == 0) {
      const ull bits = __builtin_bit_cast(ull, cn);
      const ull tag = (ull)(unsigned)(t + 1) << 32;
      ull* dst = commd + (size_t)((t + 1) & 1) * 2048 + j;
      atomic_store_u64(dst, (bits & 0xffffffffull) | tag);         // half0
      atomic_store_u64(dst + 1024, (bits >> 32) | tag);            // half1
      const int er = dir ? (TSEQ - 2 - t) : (t + 1);
      envp[(size_t)er * 2048] = (float)cn;
    }
  }
}

// ---------------- VALU f64 GEMM P3: out = tanh(env @ [wo|uo]^T + bo) ----------------
__global__ __launch_bounds__(256) void gemm_out_f64_k(
    const float* __restrict__ A, const float* __restrict__ wo,
    const float* __restrict__ uo, const float* __restrict__ bo,
    float* __restrict__ C) {
  __shared__ double As[16][66];
  __shared__ double Bs[16][66];
  const int tid = threadIdx.x;
  const int m0 = blockIdx.y * 64, n0 = blockIdx.x * 64;
  const int tx = tid & 15, ty = tid >> 4;
  const int lrow = tid >> 2, lkq = tid & 3;

  double acc[4][4] = {};

  for (int k0 = 0; k0 < 2048; k0 += 16) {
    f32x4 va = *(const f32x4*)(A + (size_t)(m0 + lrow) * 2048 + k0 + lkq * 4);
    const float* bsrc = (k0 < 1024)
        ? wo + (size_t)(n0 + lrow) * 1024 + k0 + lkq * 4
        : uo + (size_t)(n0 + lrow) * 1024 + (k0 - 1024) + lkq * 4;
    f32x4 vb = *(const f32x4*)bsrc;
    __syncthreads();
#pragma unroll
    for (int e = 0; e < 4; ++e) {
      As[lkq * 4 + e][lrow] = (double)va[e];
      Bs[lkq * 4 + e][lrow] = (double)vb[e];
    }
    __syncthreads();
#pragma unroll
    for (int k = 0; k < 16; ++k) {
      double a[4], b[4];
#pragma unroll
      for (int i = 0; i < 4; ++i) a[i] = As[k][ty + 16 * i];
#pragma unroll
      for (int jj = 0; jj < 4; ++jj) b[jj] = Bs[k][tx + 16 * jj];
#pragma unroll
      for (int i = 0; i < 4; ++i)
#pragma unroll
        for (int jj = 0; jj < 4; ++jj)
          acc[i][jj] = fma(a[i], b[jj], acc[i][jj]);
    }
  }

#pragma unroll
  for (int i = 0; i < 4; ++i)
#pragma unroll
    for (int jj = 0; jj < 4; ++jj) {
      int row = m0 + ty + 16 * i;
      int col = n0 + tx + 16 * jj;
      double s = acc[i][jj] + (double)bo[col];
      C[(size_t)row * 1024 + col] = (float)tanh(s);
    }
}

// ---------------- launch ----------------
extern "C" void kernel_launch(void* const* d_in, const int* in_sizes, int n_in,
                              void* d_out, int out_size, void* d_ws, size_t ws_size,
                              hipStream_t stream) {
  if (n_in < 24) return;
  const float* x    = (const float*)d_in[0];
  const float* wf_l = (const float*)d_in[1];
  const float* uf_l = (const float*)d_in[2];
  const float* bf_l = (const float*)d_in[3];
  const float* wi_l = (const float*)d_in[4];
  const float* ui_l = (const float*)d_in[5];
  const float* bi_l = (const float*)d_in[6];
  const float* wc_l = (const float*)d_in[7];
  const float* uc_l = (const float*)d_in[8];
  const float* bc_l = (const float*)d_in[9];
  const float* wf_r = (const float*)d_in[10];
  const float* uf_r = (const float*)d_in[11];
  const float* bf_r = (const float*)d_in[12];
  const float* wi_r = (const float*)d_in[13];
  const float* ui_r = (const float*)d_in[14];
  const float* bi_r = (const float*)d_in[15];
  const float* wc_r = (const float*)d_in[16];
  const float* uc_r = (const float*)d_in[17];
  const float* bc_r = (const float*)d_in[18];
  const float* wo   = (const float*)d_in[19];
  const float* uo   = (const float*)d_in[20];
  const float* bo   = (const float*)d_in[21];
  const float* c0l  = (const float*)d_in[22];
  const float* c0r  = (const float*)d_in[23];

  const size_t NWX = (size_t)TSEQ * 6144;
  char* p = (char*)d_ws;
  auto carve = [&](size_t bytes) -> char* {
    char* r = p; p += (bytes + 255) & ~(size_t)255; return r;
  };
  float*          WxH  = (float*)carve(NWX * 4);                  // 100.7 MB
  __hip_bfloat16* WxL  = (__hip_bfloat16*)carve(NWX * 2);         //  50.3 MB
  float*          envc = (float*)carve((size_t)TSEQ * 2048 * 4);  //  33.6 MB
  ull*            comm = (ull*)carve(8192 * 8);                   //  64 KB
  if ((size_t)(p - (char*)d_ws) > ws_size) return;

  init_k<<<8, 256, 0, stream>>>(c0l, c0r, comm, envc);

  Ptr6 Bw{{wf_l, wi_l, wc_l, wf_r, wi_r, wc_r}};
  Ptr6 Bb{{bf_l, bi_l, bc_l, bf_r, bi_r, bc_r}};
  gemm_f64v_k<<<dim3(96, 64), 256, 0, stream>>>(x, Bw, Bb, WxH, WxL);

  recur_k<<<256, 512, 0, stream>>>(uf_l, ui_l, uc_l, uf_r, ui_r, uc_r,
                                   WxH, WxL, comm, envc);

  gemm_out_f64_k<<<dim3(16, 64), 256, 0, stream>>>(envc, wo, uo, bo, (float*)d_out);
}